// Round 3
// baseline (236.487 us; speedup 1.0000x reference)
//
#include <hip/hip_runtime.h>

// MN neuron forward sim: T=1000 sequential steps, 64x512 independent chains.
// Round 5 structure: producer/consumer with DEPTH-4 LDS pipeline.
//   wave 1 (producer): global -> LDS quad-buffer via global_load_lds w=16.
//     Loads issued 3 chunks ahead; steady-state s_waitcnt vmcnt(10) means
//     "chunk c+1's 5 loads retired, chunks c+2/c+3 still in flight" -- the
//     load round-trip gets ~3 chunk-periods to complete instead of sitting
//     between consecutive barriers (rounds 2/4: depth-1, vmcnt(0) each chunk,
//     full RT on the critical path => both stuck at ~79-80us).
//   wave 0 (consumer): raw s_barrier (no store drains), chunk's 20 x values
//     batch ds_read into registers and PINNED live via asm "+v" so the
//     compiler cannot sink the reads to uses (round-4 lesson: VGPR=32 proved
//     the batch was sunk; round-3 lesson: same sinking on global loads).
//     Nontemporal fire-and-forget stores.
// CORRECTNESS: binary spike output => bit-exact f32 vs numpy ref:
//   exact reference op order, no FMA contraction, selects for spike resets.
//   mn_step is byte-identical to the verified round-2 version.
// Barrier ledger (both waves must arrive 51 times):
//   producer: B0 + 47 loop + B48 + B49 + B50 = 51; consumer: B0 + 50 = 51.
// Buffer reuse: issue(c+3)->buf[(c+3)&3]=buf[(c-1)&3] happens after B(c);
//   consumer finished reading buf[(c-1)&3] (register data dep via lgkmcnt
//   before its compute) before arriving at B(c). No race.

#define T_STEPS 1000
#define B_DIM 64
#define N_DIM 512
#define BN (B_DIM * N_DIM)   // 32768

#define K_CHUNK 20
#define NCHUNK (T_STEPS / K_CHUNK)   // 50
#define NBUF 4

// f32-rounded constants
#define C_DT   0.01f
#define C_EL   (-0.07f)
#define C_VR   (-0.07f)
#define C_TR   (-0.06f)
#define C_TINF (-0.05f)
#define C_B    12.77495288848877f
#define C_G    45.24007797241211f
#define C_K1   200.0f
#define C_K2   20.0f
#define C_R1   0.3858567178249359f
#define C_R2   (-1.1421641111373901f)

typedef const __attribute__((address_space(1))) void* gp_t;
typedef __attribute__((address_space(3))) void* lp_t;

__device__ __forceinline__ void raw_barrier() {
    // s_barrier WITHOUT the vmcnt(0)/lgkmcnt(0) drain __syncthreads() emits.
    asm volatile("s_barrier" ::: "memory");
}

__device__ __forceinline__ float mn_step(float xt, float lin, float av,
                                         float A1v, float A2v,
                                         float& V, float& i1, float& i2,
                                         float& Thr)
{
#pragma clang fp contract(off)
    i1 = i1 - (C_K1 * i1) * C_DT;
    i2 = i2 - (C_K2 * i2) * C_DT;
    float p  = lin * xt;
    float q  = p + i1;
    float r  = q + i2;
    float e  = V - C_EL;
    float g  = C_G * e;
    float s  = r - g;
    float d  = C_DT * s;
    V = V + d;
    float e2 = V - C_EL;
    float u  = av * e2;
    float w  = Thr - C_TINF;
    float bw = C_B * w;
    float s2 = u - bw;
    float d2 = C_DT * s2;
    Thr = Thr + d2;
    float diff = V - Thr;
    bool  sb   = diff > 0.0f;
    float spk  = sb ? 1.0f : 0.0f;
    float i1r = (C_R1 * i1) + A1v;
    float i2r = (C_R2 * i2) + A2v;
    i1  = sb ? i1r : i1;
    i2  = sb ? i2r : i2;
    float tm = fmaxf(Thr, C_TR);
    Thr = sb ? tm : Thr;
    V   = sb ? C_VR : V;
    return spk;
}

__global__ __launch_bounds__(128) void mn_neuron_kernel(
    const float* __restrict__ x, const float* __restrict__ linear,
    const float* __restrict__ a, const float* __restrict__ A1,
    const float* __restrict__ A2, float* __restrict__ out)
{
#pragma clang fp contract(off)
    // lds[buf][t_in_chunk][lane]
    __shared__ float lds[NBUF][K_CHUNK][64];

    const int lane = threadIdx.x & 63;
    const int wid  = threadIdx.x >> 6;     // 0 = consumer, 1 = producer
    const int blk  = blockIdx.x;

    if (wid == 1) {
        // ---- producer ----
        // width-16 global_load_lds: lane l loads 16B covering
        // row (l>>4) of the 4-row group, floats (l&15)*4 .. +3.
        // LDS dest = uniform base + l*16  ->  lds[buf][s*4 + (l>>4)][(l&15)*4..]
        const float* pl = x + (size_t)(lane >> 4) * BN
                            + (size_t)blk * 64 + (size_t)(lane & 15) * 4;

        auto issue = [&](int k) {   // issue chunk k's 5 loads into buf k&3
            const float* pc = pl + (size_t)(k * K_CHUNK) * BN;
            float* dst = &lds[k & (NBUF - 1)][0][0];
#pragma unroll
            for (int s = 0; s < K_CHUNK / 4; ++s) {
                __builtin_amdgcn_global_load_lds(
                    (gp_t)(pc + (size_t)(s * 4) * BN),
                    (lp_t)(dst + s * 4 * 64), 16, 0, 0);
            }
        };

        // prologue: 3 chunks in flight (15 loads)
        issue(0); issue(1); issue(2);
        asm volatile("s_waitcnt vmcnt(10)" ::: "memory");   // chunk 0 done
        raw_barrier();                                      // B0

        for (int c = 0; c < NCHUNK - 3; ++c) {              // c = 0..46
            issue(c + 3);
            asm volatile("s_waitcnt vmcnt(10)" ::: "memory"); // chunk c+1 done
            raw_barrier();                                  // B(c+1)
        }
        asm volatile("s_waitcnt vmcnt(5)" ::: "memory");    // chunk 48 done
        raw_barrier();                                      // B48
        asm volatile("s_waitcnt vmcnt(0)" ::: "memory");    // chunk 49 done
        raw_barrier();                                      // B49
        raw_barrier();                                      // B50
    } else {
        // ---- consumer ----
        const int idx = blk * 64 + lane;       // b*N + n
        const int n   = idx & (N_DIM - 1);

        const float lin = linear[n];
        const float av  = a[n];
        const float A1v = A1[n];
        const float A2v = A2[n];

        float V   = C_EL;
        float i1  = 0.0f;
        float i2  = 0.0f;
        float Thr = C_TINF;

        float* op = out + idx;

        raw_barrier();   // B0: buf0 ready

        for (int c = 0; c < NCHUNK; ++c) {
            const float* src = &lds[c & (NBUF - 1)][0][lane];

            // Batch the chunk's 20 ds_read_b32 (imm offsets j*256; 2-way bank
            // alias = free), then PIN each value live in a VGPR. The pin makes
            // sinking impossible: one pipelined LDS latency per chunk instead
            // of per-step exposure (round-4's VGPR=32 proved the sink).
            float xv[K_CHUNK];
#pragma unroll
            for (int j = 0; j < K_CHUNK; ++j)
                xv[j] = src[j * 64];
#pragma unroll
            for (int j = 0; j < K_CHUNK; ++j)
                asm volatile("" : "+v"(xv[j]));

#pragma unroll
            for (int j = 0; j < K_CHUNK; ++j) {
                float spk = mn_step(xv[j], lin, av, A1v, A2v, V, i1, i2, Thr);
                __builtin_nontemporal_store(spk, op);
                op += BN;
            }
            raw_barrier();   // B(c+1): fire-and-forget stores, no vmcnt drain
        }
    }
}

extern "C" void kernel_launch(void* const* d_in, const int* in_sizes, int n_in,
                              void* d_out, int out_size, void* d_ws, size_t ws_size,
                              hipStream_t stream) {
    const float* x      = (const float*)d_in[0];
    const float* linear = (const float*)d_in[1];
    const float* a      = (const float*)d_in[2];
    const float* A1     = (const float*)d_in[3];
    const float* A2     = (const float*)d_in[4];
    float* out = (float*)d_out;

    // 512 blocks x 128 threads (1 consumer wave + 1 producer wave each)
    mn_neuron_kernel<<<BN / 64, 128, 0, stream>>>(x, linear, a, A1, A2, out);
}